// Round 1
// 330.151 us; speedup vs baseline: 1.0166x; 1.0166x over previous
//
#include <hip/hip_runtime.h>
#include <hip/hip_bf16.h>
#include <math.h>

#define NNODES 50000
#define NEDGES 500000
#define ETOT   (NEDGES + NNODES)
#define DIN    128
#define CH     256
#define SLOPE  0.2f

#define SCAN_TILE 1024
#define NSCAN ((NNODES + SCAN_TILE - 1) / SCAN_TILE)   // 49

typedef __attribute__((ext_vector_type(8))) short short8;
typedef __attribute__((ext_vector_type(4))) float f32x4;

static __device__ __forceinline__ float wave_reduce_max(float v) {
#pragma unroll
  for (int off = 32; off > 0; off >>= 1) v = fmaxf(v, __shfl_xor(v, off));
  return v;
}
static __device__ __forceinline__ float wave_reduce_sum(float v) {
#pragma unroll
  for (int off = 32; off > 0; off >>= 1) v += __shfl_xor(v, off);
  return v;
}

static __device__ __forceinline__ unsigned short f2bf(float f) {
  unsigned int u = __float_as_uint(f);
  unsigned int r = (u + 0x7fffu + ((u >> 16) & 1u)) >> 16;
  return (unsigned short)r;
}
static __device__ __forceinline__ float bf2f(unsigned short u) {
  return __uint_as_float(((unsigned int)u) << 16);
}

// ---------------- fused init + weight cast: one dispatch ----------------
#define W1N4 (CH * DIN / 4)   // 8192
#define W2N4 (CH * CH / 4)    // 16384
__global__ __launch_bounds__(256) void init_and_cast(
    int* __restrict__ deg,
    float* __restrict__ eS1, float* __restrict__ eD1,
    float* __restrict__ eS2, float* __restrict__ eD2,
    const float* __restrict__ W1, const float* __restrict__ W2,
    unsigned short* __restrict__ Wb1, unsigned short* __restrict__ Wb2) {
  int i = blockIdx.x * 256 + threadIdx.x;
  if (i < NNODES) {
    deg[i] = 0;
    eS1[i] = 0.f; eD1[i] = 0.f;
    eS2[i] = 0.f; eD2[i] = 0.f;
  }
  if (i < W1N4 + W2N4) {
    const float* src;
    unsigned short* dst;
    int j;
    if (i < W1N4) { src = W1; dst = Wb1; j = i; }
    else          { src = W2; dst = Wb2; j = i - W1N4; }
    float4 v = *(const float4*)(src + (size_t)j * 4);
    ushort4 o;
    o.x = f2bf(v.x); o.y = f2bf(v.y); o.z = f2bf(v.z); o.w = f2bf(v.w);
    *(ushort4*)(dst + (size_t)j * 4) = o;
  }
}

// ---------------- CSR build pieces ----------------
__global__ __launch_bounds__(256) void scan_blocksums(const int* __restrict__ deg,
                                                      int* __restrict__ bsums) {
  __shared__ int sdata[4];
  int b = blockIdx.x;
  int tid = threadIdx.x;
  int idx = b * SCAN_TILE + tid * 4;
  int s = 0;
  if (idx + 3 < NNODES) {
    int4 v = *(const int4*)(deg + idx);
    s = v.x + v.y + v.z + v.w;
  } else {
#pragma unroll
    for (int j = 0; j < 4; j++) if (idx + j < NNODES) s += deg[idx + j];
  }
#pragma unroll
  for (int off = 32; off > 0; off >>= 1) s += __shfl_xor(s, off);
  if ((tid & 63) == 0) sdata[tid >> 6] = s;
  __syncthreads();
  if (tid == 0) bsums[b] = sdata[0] + sdata[1] + sdata[2] + sdata[3];
}

__global__ __launch_bounds__(64) void scan_bsums(const int* __restrict__ bsums,
                                                 int* __restrict__ boffs,
                                                 int* __restrict__ rowptr) {
  int tid = threadIdx.x;
  int v = (tid < NSCAN) ? bsums[tid] : 0;
  int x = v;
#pragma unroll
  for (int off = 1; off < 64; off <<= 1) {
    int t = __shfl_up(x, off);
    if (tid >= off) x += t;
  }
  if (tid < NSCAN) boffs[tid] = x - v;
  if (tid == 63) rowptr[NNODES] = x;
}

__global__ __launch_bounds__(256) void scan_final(const int* __restrict__ deg,
                                                  const int* __restrict__ boffs,
                                                  int* __restrict__ rowptr,
                                                  int* __restrict__ cursor) {
  __shared__ int wsums[4];
  int b = blockIdx.x;
  int tid = threadIdx.x;
  int lane = tid & 63;
  int base = b * SCAN_TILE + tid * 4;
  int d[4];
  int s = 0;
#pragma unroll
  for (int j = 0; j < 4; j++) {
    d[j] = (base + j < NNODES) ? deg[base + j] : 0;
    s += d[j];
  }
  int x = s;
#pragma unroll
  for (int off = 1; off < 64; off <<= 1) {
    int t = __shfl_up(x, off);
    if (lane >= off) x += t;
  }
  if (lane == 63) wsums[tid >> 6] = x;
  __syncthreads();
  int woff = 0;
  int w = tid >> 6;
  for (int i = 0; i < w; i++) woff += wsums[i];
  int excl = boffs[b] + woff + (x - s);
#pragma unroll
  for (int j = 0; j < 4; j++) {
    if (base + j < NNODES) { rowptr[base + j] = excl; cursor[base + j] = excl; }
    excl += d[j];
  }
}

__global__ void scatter_kernel(const int* __restrict__ ei, int* __restrict__ cursor,
                               int* __restrict__ csr_src) {
  int e = blockIdx.x * blockDim.x + threadIdx.x;
  if (e >= ETOT) return;
  int src, dst;
  if (e < NEDGES) { src = ei[e]; dst = ei[NEDGES + e]; }
  else            { src = e - NEDGES; dst = src; }
  int slot = atomicAdd(&cursor[dst], 1);
  csr_src[slot] = src;
}

// ---------------- bf16 MFMA GEMM body + fused attention-score epilogue ----------------
#define TM 128
#define TN 128
#define TK 64
#define LDA (TK + 8)
#define LDC (TN + 8)
#define GEMM_GRID (2 * ((NNODES + TM - 1) / TM))      // 782
#define DEG_BLOCKS ((ETOT + 255) / 256)               // 2149

static __device__ __forceinline__ void gemm_body(
    const float* __restrict__ Xf, const unsigned short* __restrict__ Xb, int ldx,
    const unsigned short* __restrict__ W, int K,
    unsigned short* __restrict__ Hout, int M,
    const float* __restrict__ a_src, const float* __restrict__ a_dst,
    float* __restrict__ eS, float* __restrict__ eD,
    int bm, int bn) {
  __shared__ short smem[TM * LDA * 2];   // As | Bs ; reused as Cs
  short* As = smem;
  short* Bs = smem + TM * LDA;
  short* Cs = smem;
  int tid = threadIdx.x;
  int wid = tid >> 6;
  int lane = tid & 63;
  int wm = (wid & 1) * 64;
  int wn = (wid >> 1) * 64;
  int lrow = lane & 15;
  int lk8 = (lane >> 4) * 8;

  int srow = tid >> 3;
  int skoff = (tid & 7) * 8;

  f32x4 acc[4][4] = {};

  for (int k0 = 0; k0 < K; k0 += TK) {
#pragma unroll
    for (int i = 0; i < 4; i++) {
      int r = srow + 32 * i;
      int gm = bm + r;
      short8 v = {};
      if (gm < M) {
        if (Xf) {
          const float* p = Xf + (size_t)gm * ldx + k0 + skoff;
          float4 f0 = *(const float4*)(p);
          float4 f1 = *(const float4*)(p + 4);
          v[0] = (short)f2bf(f0.x); v[1] = (short)f2bf(f0.y);
          v[2] = (short)f2bf(f0.z); v[3] = (short)f2bf(f0.w);
          v[4] = (short)f2bf(f1.x); v[5] = (short)f2bf(f1.y);
          v[6] = (short)f2bf(f1.z); v[7] = (short)f2bf(f1.w);
        } else {
          v = *(const short8*)(Xb + (size_t)gm * ldx + k0 + skoff);
        }
      }
      *(short8*)(&As[r * LDA + skoff]) = v;
      short8 w = *(const short8*)(W + (size_t)(bn + r) * K + k0 + skoff);
      *(short8*)(&Bs[r * LDA + skoff]) = w;
    }
    __syncthreads();
#pragma unroll
    for (int kk = 0; kk < TK; kk += 32) {
      short8 a[4], b[4];
#pragma unroll
      for (int mi = 0; mi < 4; mi++)
        a[mi] = *(const short8*)(&As[(wm + mi * 16 + lrow) * LDA + kk + lk8]);
#pragma unroll
      for (int ni = 0; ni < 4; ni++)
        b[ni] = *(const short8*)(&Bs[(wn + ni * 16 + lrow) * LDA + kk + lk8]);
#pragma unroll
      for (int mi = 0; mi < 4; mi++)
#pragma unroll
        for (int ni = 0; ni < 4; ni++)
          acc[mi][ni] = __builtin_amdgcn_mfma_f32_16x16x32_bf16(a[mi], b[ni], acc[mi][ni], 0, 0, 0);
    }
    __syncthreads();
  }

  int crow = (lane >> 4) * 4;
  int ccol = lane & 15;

  // ---- fused score epilogue ----
  float asv[4], adv[4];
#pragma unroll
  for (int ni = 0; ni < 4; ni++) {
    int c = bn + wn + ni * 16 + ccol;
    asv[ni] = a_src[c];
    adv[ni] = a_dst[c];
  }
#pragma unroll
  for (int mi = 0; mi < 4; mi++) {
#pragma unroll
    for (int r = 0; r < 4; r++) {
      float s = 0.f, d = 0.f;
#pragma unroll
      for (int ni = 0; ni < 4; ni++) {
        float h = acc[mi][ni][r];
        s += h * asv[ni];
        d += h * adv[ni];
      }
#pragma unroll
      for (int off = 1; off < 16; off <<= 1) {
        s += __shfl_xor(s, off);
        d += __shfl_xor(d, off);
      }
      int gm = bm + wm + mi * 16 + crow + r;
      if (ccol == 0 && gm < M) {
        atomicAdd(&eS[gm], s);
        atomicAdd(&eD[gm], d);
      }
    }
  }

  // ---- C-store via padded LDS tile -> coalesced short8 global stores ----
#pragma unroll
  for (int mi = 0; mi < 4; mi++) {
#pragma unroll
    for (int ni = 0; ni < 4; ni++) {
#pragma unroll
      for (int r = 0; r < 4; r++) {
        int row = wm + mi * 16 + crow + r;
        int col = wn + ni * 16 + ccol;
        Cs[row * LDC + col] = (short)f2bf(acc[mi][ni][r]);
      }
    }
  }
  __syncthreads();
  int orow = tid >> 4;
  int ocol = (tid & 15) * 8;
#pragma unroll
  for (int pp = 0; pp < 8; pp++) {
    int row = pp * 16 + orow;
    int gm = bm + row;
    if (gm < M) {
      short8 v = *(const short8*)(&Cs[row * LDC + ocol]);
      *(short8*)(&Hout[(size_t)gm * CH + bn + ocol]) = v;
    }
  }
}

// layer-1 GEMM with degree-count blocks fused at the grid tail (independent work
// overlaps: degree atomics hide under MFMA/staging of the GEMM blocks)
__global__ __launch_bounds__(256) void gemm1_deg(
    const float* __restrict__ Xf, const unsigned short* __restrict__ W,
    unsigned short* __restrict__ Hout,
    const float* __restrict__ a_src, const float* __restrict__ a_dst,
    float* __restrict__ eS, float* __restrict__ eD,
    const int* __restrict__ ei, int* __restrict__ deg) {
  if (blockIdx.x >= GEMM_GRID) {
    int e = (blockIdx.x - GEMM_GRID) * 256 + threadIdx.x;
    if (e < ETOT) {
      int dst = (e < NEDGES) ? ei[NEDGES + e] : (e - NEDGES);
      atomicAdd(&deg[dst], 1);
    }
    return;
  }
  int bn = (blockIdx.x & 1) * TN;
  int bm = (blockIdx.x >> 1) * TM;
  gemm_body(Xf, (const unsigned short*)nullptr, DIN, W, DIN, Hout, NNODES,
            a_src, a_dst, eS, eD, bm, bn);
}

__global__ __launch_bounds__(256) void gemm_l2(
    const unsigned short* __restrict__ Xb, const unsigned short* __restrict__ W,
    unsigned short* __restrict__ Hout,
    const float* __restrict__ a_src, const float* __restrict__ a_dst,
    float* __restrict__ eS, float* __restrict__ eD) {
  int bn = blockIdx.x * TN;
  int bm = blockIdx.y * TM;
  gemm_body((const float*)nullptr, Xb, CH, W, CH, Hout, NNODES,
            a_src, a_dst, eS, eD, bm, bn);
}

// ---------------- per-node softmax + aggregate (+bias, +ReLU) ----------------
// Wave per node (4/block). Weighted pass: half-wave (32 lanes) per edge, each
// lane loads uint4 (16 B) -> one VMEM instr covers TWO edges' 512 B rows;
// 8 loads keep 16 edges in flight; 1 bpermute broadcast per edge.
__global__ __launch_bounds__(256) void aggregate_kernel(
    const unsigned short* __restrict__ Hmb, const float* __restrict__ eS,
    const float* __restrict__ eD, const int* __restrict__ rowptr,
    const int* __restrict__ csr_src, const float* __restrict__ bias,
    float* __restrict__ out, int outOffset, unsigned short* __restrict__ xout) {
  int n = blockIdx.x * 4 + (threadIdx.x >> 6);
  if (n >= NNODES) return;
  int lane = threadIdx.x & 63;
  int half = lane >> 5;        // which edge of the pair this lane serves
  int cg = lane & 31;          // channel group: channels cg*8 .. cg*8+7
  int beg = rowptr[n], end = rowptr[n + 1];
  int deg = end - beg;
  float ed = eD[n];

  float acc8[8];
#pragma unroll
  for (int k = 0; k < 8; k++) acc8[k] = 0.f;

  if (deg <= 64) {
    int src = 0;
    float e = -1e30f;
    if (lane < deg) {
      src = csr_src[beg + lane];              // coalesced
      float t = eS[src] + ed;                 // lane-parallel gather
      e = (t >= 0.f) ? t : SLOPE * t;
    }
    float m = wave_reduce_max(e);
    float p = (lane < deg) ? __expf(e - m) : 0.f;
    float inv = 1.f / (wave_reduce_sum(p) + 1e-16f);
    float av = p * inv;                       // this lane's alpha

    for (int j0 = 0; j0 < deg; j0 += 16) {
      uint4 hv[8];
      float al[8];
#pragma unroll
      for (int t = 0; t < 8; t++) {
        int j = j0 + 2 * t + half;
        int jj = (j < deg) ? j : deg - 1;     // tail dups last edge (L1-hot)
        int sj = __shfl(src, jj);
        float aj = __shfl(av, jj);
        al[t] = (j < deg) ? aj : 0.f;
        hv[t] = *(const uint4*)(Hmb + (size_t)sj * CH + cg * 8);
      }
#pragma unroll
      for (int t = 0; t < 8; t++) {
        acc8[0] += al[t] * __uint_as_float(hv[t].x << 16);
        acc8[1] += al[t] * __uint_as_float(hv[t].x & 0xffff0000u);
        acc8[2] += al[t] * __uint_as_float(hv[t].y << 16);
        acc8[3] += al[t] * __uint_as_float(hv[t].y & 0xffff0000u);
        acc8[4] += al[t] * __uint_as_float(hv[t].z << 16);
        acc8[5] += al[t] * __uint_as_float(hv[t].z & 0xffff0000u);
        acc8[6] += al[t] * __uint_as_float(hv[t].w << 16);
        acc8[7] += al[t] * __uint_as_float(hv[t].w & 0xffff0000u);
      }
    }
  } else {
    float m = -1e30f;
    for (int i = lane; i < deg; i += 64) {
      float e = eS[csr_src[beg + i]] + ed;
      e = (e >= 0.f) ? e : SLOPE * e;
      m = fmaxf(m, e);
    }
    m = wave_reduce_max(m);
    float ds = 0.f;
    for (int i = lane; i < deg; i += 64) {
      float e = eS[csr_src[beg + i]] + ed;
      e = (e >= 0.f) ? e : SLOPE * e;
      ds += __expf(e - m);
    }
    float inv = 1.f / (wave_reduce_sum(ds) + 1e-16f);
    for (int j = 0; j < deg; j += 2) {
      int jj = j + half;
      int k = beg + ((jj < deg) ? jj : deg - 1);
      int s = csr_src[k];
      float e = eS[s] + ed;
      e = (e >= 0.f) ? e : SLOPE * e;
      float alpha = (jj < deg) ? __expf(e - m) * inv : 0.f;
      uint4 u = *(const uint4*)(Hmb + (size_t)s * CH + cg * 8);
      acc8[0] += alpha * __uint_as_float(u.x << 16);
      acc8[1] += alpha * __uint_as_float(u.x & 0xffff0000u);
      acc8[2] += alpha * __uint_as_float(u.y << 16);
      acc8[3] += alpha * __uint_as_float(u.y & 0xffff0000u);
      acc8[4] += alpha * __uint_as_float(u.z << 16);
      acc8[5] += alpha * __uint_as_float(u.z & 0xffff0000u);
      acc8[6] += alpha * __uint_as_float(u.w << 16);
      acc8[7] += alpha * __uint_as_float(u.w & 0xffff0000u);
    }
  }

  // combine the two half-wave partial sums (even-j half + odd-j half)
#pragma unroll
  for (int k = 0; k < 8; k++) acc8[k] += __shfl_xor(acc8[k], 32);

  // lane writes 4 channels: cbase = cg*8 + half*4 (static-index selects only)
  float a0 = half ? acc8[4] : acc8[0];
  float a1 = half ? acc8[5] : acc8[1];
  float a2 = half ? acc8[6] : acc8[2];
  float a3 = half ? acc8[7] : acc8[3];
  int cbase = cg * 8 + half * 4;
  float4 b = *(const float4*)(bias + cbase);
  float4 o;
  o.x = fmaxf(a0 + b.x, 0.f);
  o.y = fmaxf(a1 + b.y, 0.f);
  o.z = fmaxf(a2 + b.z, 0.f);
  o.w = fmaxf(a3 + b.w, 0.f);
  *(float4*)(out + (size_t)n * 512 + outOffset + cbase) = o;
  if (xout) {
    ushort4 ob;
    ob.x = f2bf(o.x); ob.y = f2bf(o.y); ob.z = f2bf(o.z); ob.w = f2bf(o.w);
    *(ushort4*)(xout + (size_t)n * CH + cbase) = ob;
  }
}

extern "C" void kernel_launch(void* const* d_in, const int* in_sizes, int n_in,
                              void* d_out, int out_size, void* d_ws, size_t ws_size,
                              hipStream_t stream) {
  const float* x   = (const float*)d_in[0];
  const int*   ei  = (const int*)d_in[1];
  const float* W1  = (const float*)d_in[2];
  const float* a1s = (const float*)d_in[3];
  const float* a1d = (const float*)d_in[4];
  const float* b1  = (const float*)d_in[5];
  const float* W2  = (const float*)d_in[6];
  const float* a2s = (const float*)d_in[7];
  const float* a2d = (const float*)d_in[8];
  const float* b2  = (const float*)d_in[9];
  float* out = (float*)d_out;

  char* ws = (char*)d_ws;
  size_t off = 0;
  auto alloc = [&](size_t bytes) -> void* {
    void* p = ws + off;
    off = (off + bytes + 255) & ~(size_t)255;
    return p;
  };
  unsigned short* Hmb    = (unsigned short*)alloc(sizeof(short) * (size_t)NNODES * CH);
  unsigned short* Xb     = (unsigned short*)alloc(sizeof(short) * (size_t)NNODES * CH);
  unsigned short* Wb1    = (unsigned short*)alloc(sizeof(short) * CH * DIN);
  unsigned short* Wb2    = (unsigned short*)alloc(sizeof(short) * CH * CH);
  float*          eS1    = (float*)alloc(sizeof(float) * NNODES);
  float*          eD1    = (float*)alloc(sizeof(float) * NNODES);
  float*          eS2    = (float*)alloc(sizeof(float) * NNODES);
  float*          eD2    = (float*)alloc(sizeof(float) * NNODES);
  int*            rowptr = (int*)alloc(sizeof(int) * (NNODES + 1));
  int*            cursor = (int*)alloc(sizeof(int) * NNODES);
  int*            csrsrc = (int*)alloc(sizeof(int) * ETOT);
  int*            deg    = (int*)alloc(sizeof(int) * NNODES);
  int*            bsums  = (int*)alloc(sizeof(int) * NSCAN);
  int*            boffs  = (int*)alloc(sizeof(int) * NSCAN);

  int nblk4 = (NNODES + 3) / 4;

  // init + weight casts (1 dispatch)
  init_and_cast<<<(NNODES + 255) / 256, 256, 0, stream>>>(deg, eS1, eD1, eS2, eD2,
                                                          W1, W2, Wb1, Wb2);

  // layer-1 GEMM with degree counting fused at the grid tail (overlapped)
  gemm1_deg<<<GEMM_GRID + DEG_BLOCKS, 256, 0, stream>>>(x, Wb1, Hmb, a1s, a1d,
                                                        eS1, eD1, ei, deg);

  // CSR build (edge list identical for both layers)
  scan_blocksums<<<NSCAN, 256, 0, stream>>>(deg, bsums);
  scan_bsums<<<1, 64, 0, stream>>>(bsums, boffs, rowptr);
  scan_final<<<NSCAN, 256, 0, stream>>>(deg, boffs, rowptr, cursor);
  scatter_kernel<<<(ETOT + 255) / 256, 256, 0, stream>>>(ei, cursor, csrsrc);

  // layer 1 aggregate
  aggregate_kernel<<<nblk4, 256, 0, stream>>>(Hmb, eS1, eD1, rowptr, csrsrc, b1, out, 0, Xb);

  // layer 2
  gemm_l2<<<dim3(2, (NNODES + TM - 1) / TM), 256, 0, stream>>>(Xb, Wb2, Hmb, a2s, a2d, eS2, eD2);
  aggregate_kernel<<<nblk4, 256, 0, stream>>>(Hmb, eS2, eD2, rowptr, csrsrc, b2, out, 256,
                                              (unsigned short*)nullptr);
}